// Round 15
// baseline (106.919 us; speedup 1.0000x reference)
//
#include <hip/hip_runtime.h>

#define EPS 1e-20f
typedef float f4 __attribute__((ext_vector_type(4)));

__device__ __forceinline__ float softplus(float x) {
    return fmaxf(x, 0.f) + log1pf(expf(-fabsf(x)));
}

// Self-contained fused kernel (prep_weights folded in; no workspace).
// Structure = fused6 (R11 champion): tile = (b, h, ct-half) = 1 row x 128 cols x 32 ch,
// grid 2048, 4 blocks/CU. Single A/B delta vs fused6: sp loads are PLAIN (no NT hint).
// Stage 1: wave w, iter 0..3: c = w*8 + iter*2 + (lane>>5), quad pq = lane&31.
//   -> each global load instruction = two dense 512B segments (one per channel).
// Stage 2: thread (og = tid>>5, pq = tid&31): 4 outputs x 4 px from LDS.
__global__ __launch_bounds__(256) void fused10(
    const float* __restrict__ d,
    const float* __restrict__ cd,
    const float* __restrict__ sp,     // [B,Cin,9,H,W]
    const float* __restrict__ channel_weight,  // [32*32] = [o][c]
    const float* __restrict__ spatial_weight,  // [32*9]
    const float* __restrict__ bias,   // [32]
    float* __restrict__ out)          // d_out [4,32,256,256] then cd_out
{
    __shared__ float lt[32 * 128];    // nom*inv_sum_sw,  [c][pq*4 + p]
    __shared__ float lc[32 * 128];    // cdsp = den*inv_sum_sw
    __shared__ float lcw[1024];       // softplus(channel_weight) transposed [c*32+o]
    __shared__ float lsw[288];        // softplus(spatial_weight)  [c*9+k]
    __shared__ float red[8];          // per-wave partial sums
    __shared__ float linv[2];         // 1/sum(sw), 1/sum(cw)

    const int plane = 65536;
    const int tid = threadIdx.x;

    // ---------------- folded weight prep (identical across blocks) ----------------
    {
        float psw = 0.f, pcw = 0.f;
        #pragma unroll
        for (int t = 0; t < 2; ++t) {              // 288 = 256 + 32
            const int i = t * 256 + tid;
            if (i < 288) {
                const float v = softplus(spatial_weight[i]);
                lsw[i] = v;
                psw += v;
            }
        }
        #pragma unroll
        for (int t = 0; t < 4; ++t) {              // 1024 values, i = o*32+c
            const int i = t * 256 + tid;
            const float v = softplus(channel_weight[i]);
            lcw[(i & 31) * 32 + (i >> 5)] = v;     // transposed store
            pcw += v;
        }
        // wave-level reduce (64 lanes), then cross-wave via LDS
        #pragma unroll
        for (int s = 32; s > 0; s >>= 1) {
            psw += __shfl_xor(psw, s, 64);
            pcw += __shfl_xor(pcw, s, 64);
        }
        if ((tid & 63) == 0) {
            red[tid >> 6] = psw;
            red[4 + (tid >> 6)] = pcw;
        }
        __syncthreads();
        if (tid == 0) {
            linv[0] = 1.0f / (red[0] + red[1] + red[2] + red[3]);
            linv[1] = 1.0f / (red[4] + red[5] + red[6] + red[7]);
        }
        __syncthreads();
    }

    // chunked XCD swizzle: XCD k (= orig%8) gets 256 consecutive bids (2048 % 8 == 0)
    int bid = blockIdx.x;
    bid = (bid & 7) * 256 + (bid >> 3);

    const int ct = bid & 1;           // column half
    const int h  = (bid >> 1) & 255;
    const int b  = bid >> 9;

    // ---------------- stage 1 ----------------
    const int w    = tid >> 6;        // wave 0..3
    const int half = (tid >> 5) & 1;  // channel parity within wave
    const int pq   = tid & 31;        // quad within half-row
    const int col0 = ct * 128 + pq * 4;
    const float inv_sum_sw = linv[0];
    const bool rowv0 = (h >= 1), rowv2 = (h <= 254);

    #pragma unroll 1
    for (int iter = 0; iter < 4; ++iter) {
        const int c  = w * 8 + iter * 2 + half;
        const int bc = b * 32 + c;
        const float* __restrict__ dC  = d  + (size_t)bc * plane;
        const float* __restrict__ cdC = cd + (size_t)bc * plane;
        const float* __restrict__ spC = sp + (size_t)bc * 9 * plane + h * 256;

        f4 spv[9];
        #pragma unroll
        for (int k = 0; k < 9; ++k)
            spv[k] = *(const f4*)(spC + (size_t)k * plane + col0);   // PLAIN load (A/B vs NT)

        float dr[3][6], cr[3][6];     // cols col0-1 .. col0+4
        #pragma unroll
        for (int i = 0; i < 3; ++i) {
            const int hh = h + i - 1;
            const int hc = min(max(hh, 0), 255);
            const float* __restrict__ drow = dC  + hc * 256;
            const float* __restrict__ crow = cdC + hc * 256;
            f4 dv = *(const f4*)(drow + col0);
            f4 cv = *(const f4*)(crow + col0);
            dr[i][1] = dv[0]; dr[i][2] = dv[1]; dr[i][3] = dv[2]; dr[i][4] = dv[3];
            cr[i][1] = cv[0]; cr[i][2] = cv[1]; cr[i][3] = cv[2]; cr[i][4] = cv[3];
            dr[i][0] = drow[max(col0 - 1, 0)];
            cr[i][0] = crow[max(col0 - 1, 0)];
            dr[i][5] = drow[min(col0 + 4, 255)];
            cr[i][5] = crow[min(col0 + 4, 255)];
        }

        float swk[9];
        #pragma unroll
        for (int k = 0; k < 9; ++k) swk[k] = lsw[c * 9 + k];   // LDS broadcast per half-wave

        float nom[4] = {0.f, 0.f, 0.f, 0.f}, den[4] = {0.f, 0.f, 0.f, 0.f};
        #pragma unroll
        for (int i = 0; i < 3; ++i) {
            const bool rv = (i == 0) ? rowv0 : ((i == 2) ? rowv2 : true);
            #pragma unroll
            for (int j = 0; j < 3; ++j) {
                const int k = i * 3 + j;
                const float s = swk[k];
                #pragma unroll
                for (int p = 0; p < 4; ++p) {
                    const int ww = col0 + p + j - 1;
                    const bool valid = rv && ((unsigned)ww < 256u);
                    const float cdp = valid ? cr[i][p + j] * spv[k][p] : 0.f;
                    nom[p] = fmaf(cdp * dr[i][p + j], s, nom[p]);
                    den[p] = fmaf(cdp, s, den[p]);
                }
            }
        }

        // t = cdsp*dsp = (den*inv)*(nom/(den+EPS)) ~= nom*inv  (rel err EPS/(den+EPS))
        f4 tv, cv4;
        #pragma unroll
        for (int p = 0; p < 4; ++p) {
            tv[p]  = nom[p] * inv_sum_sw;
            cv4[p] = den[p] * inv_sum_sw;
        }
        *(f4*)&lt[c * 128 + pq * 4] = tv;      // single ds_write_b128
        *(f4*)&lc[c * 128 + pq * 4] = cv4;
    }

    __syncthreads();

    // ---------------- stage 2 ----------------
    const int og = tid >> 5;          // 0..7 -> o = og*4 .. og*4+3
    const int o0 = og * 4;

    float n2[4][4], d2[4][4];
    #pragma unroll
    for (int oi = 0; oi < 4; ++oi)
        #pragma unroll
        for (int j = 0; j < 4; ++j) { n2[oi][j] = 0.f; d2[oi][j] = 0.f; }

    for (int cc = 0; cc < 32; ++cc) {
        const f4 tq = *(const f4*)&lt[cc * 128 + pq * 4];   // ds_read_b128
        const f4 cq = *(const f4*)&lc[cc * 128 + pq * 4];   // lanes l/l+32 broadcast
        const f4 cw4 = *(const f4*)&lcw[cc * 32 + o0];
        #pragma unroll
        for (int oi = 0; oi < 4; ++oi)
            #pragma unroll
            for (int j = 0; j < 4; ++j) {
                n2[oi][j] = fmaf(tq[j], cw4[oi], n2[oi][j]);
                d2[oi][j] = fmaf(cq[j], cw4[oi], d2[oi][j]);
            }
    }

    const float inv_sum_cw = linv[1];
    const f4 b4 = *(const f4*)&bias[o0];
    const int colb = ct * 128 + pq * 4;

    #pragma unroll
    for (int oi = 0; oi < 4; ++oi) {
        f4 dv, cv;
        #pragma unroll
        for (int j = 0; j < 4; ++j) {
            dv[j] = n2[oi][j] / (d2[oi][j] + EPS) + b4[oi];
            cv[j] = d2[oi][j] * inv_sum_cw;   // STRIDE=1
        }
        const size_t po = (size_t)(b * 32 + o0 + oi) * plane + h * 256 + colb;
        *(f4*)(out + po)           = dv;
        *(f4*)(out + 8388608 + po) = cv;
    }
}

extern "C" void kernel_launch(void* const* d_in, const int* in_sizes, int n_in,
                              void* d_out, int out_size, void* d_ws, size_t ws_size,
                              hipStream_t stream) {
    const float* d    = (const float*)d_in[0];
    const float* cd   = (const float*)d_in[1];
    // d_in[2] = s, d_in[3] = cs : unused in forward
    const float* sp   = (const float*)d_in[4];
    const float* cwt  = (const float*)d_in[5];
    const float* swt  = (const float*)d_in[6];
    const float* bias = (const float*)d_in[7];
    float* out = (float*)d_out;

    fused10<<<2048, 256, 0, stream>>>(d, cd, sp, cwt, swt, bias, out);
}

// Round 16
// 94.301 us; speedup vs baseline: 1.1338x; 1.1338x over previous
//
#include <hip/hip_runtime.h>

#define EPS 1e-20f
typedef float f4 __attribute__((ext_vector_type(4)));

// ws layout (floats): [0,288)   sw  = softplus(spatial_weight) [c*9+k]
//                     [288,1312) cwT = softplus(channel_weight) transposed [c*32+o]
//                     [1312] 1/sum(sw), [1313] 1/sum(cw)
__global__ void prep_weights(const float* __restrict__ channel_weight, // [32*32] = [o][c]
                             const float* __restrict__ spatial_weight, // [32*9]
                             float* __restrict__ ws) {
    __shared__ float red[256];
    int tid = threadIdx.x;
    float local_sw = 0.f, local_cw = 0.f;
    for (int i = tid; i < 288; i += 256) {
        float x = spatial_weight[i];
        float v = fmaxf(x, 0.f) + log1pf(expf(-fabsf(x)));
        ws[i] = v;
        local_sw += v;
    }
    for (int i = tid; i < 1024; i += 256) {
        float x = channel_weight[i];   // i = o*32 + c
        float v = fmaxf(x, 0.f) + log1pf(expf(-fabsf(x)));
        int o = i >> 5, c = i & 31;
        ws[288 + c * 32 + o] = v;      // transposed store
        local_cw += v;
    }
    red[tid] = local_sw;
    __syncthreads();
    for (int s = 128; s > 0; s >>= 1) {
        if (tid < s) red[tid] += red[tid + s];
        __syncthreads();
    }
    if (tid == 0) ws[1312] = 1.0f / red[0];
    __syncthreads();
    red[tid] = local_cw;
    __syncthreads();
    for (int s = 128; s > 0; s >>= 1) {
        if (tid < s) red[tid] += red[tid + s];
        __syncthreads();
    }
    if (tid == 0) ws[1313] = 1.0f / red[0];
}

// fused6 (R11 champion, 94.1us) + ONE delta: software-pipelined stage 1.
// sp (69% of bytes) is double-buffered in registers (A/B, 9 x f4 each, static
// indexing only): per iter we issue d/cd loads, then the NEXT iter's sp NT loads,
// then FMA on the CURRENT sp buffer — in-order vmcnt means the FMAs wait only on
// d/cd while the next sp tile's ~900cy HBM latency hides under compute+LDS store.
// Tile = (b, h, ct-half) = 1 row x 128 cols x 32 ch; grid 2048; LDS 36.9KB (4 blk/CU).
__global__ __launch_bounds__(256) void fused11(
    const float* __restrict__ d,
    const float* __restrict__ cd,
    const float* __restrict__ sp,     // [B,Cin,9,H,W]
    const float* __restrict__ wsbuf,
    const float* __restrict__ bias,   // [32]
    float* __restrict__ out)          // d_out [4,32,256,256] then cd_out
{
    __shared__ float lt[32 * 128];    // nom*inv_sum_sw,  [c][pq*4 + p]
    __shared__ float lc[32 * 128];    // cdsp = den*inv_sum_sw
    __shared__ float lcw[1024];       // [c][o]

    const int plane = 65536;

    // chunked XCD swizzle: XCD k (= orig%8) gets 256 consecutive bids (2048 % 8 == 0)
    int bid = blockIdx.x;
    bid = (bid & 7) * 256 + (bid >> 3);

    const int ct = bid & 1;           // column half
    const int h  = (bid >> 1) & 255;
    const int b  = bid >> 9;

    const int tid = threadIdx.x;

    // cooperative: channel weights -> LDS (consumed after the barrier)
    #pragma unroll
    for (int i = 0; i < 4; ++i) lcw[i * 256 + tid] = wsbuf[288 + i * 256 + tid];

    const int w    = tid >> 6;        // wave 0..3
    const int half = (tid >> 5) & 1;  // channel parity within wave
    const int pq   = tid & 31;        // quad within half-row
    const int col0 = ct * 128 + pq * 4;
    const float inv_sum_sw = wsbuf[1312];
    const bool rowv0 = (h >= 1), rowv2 = (h <= 254);

    f4 A[9], B[9];                    // sp double buffer (static indexing only)

#define ISSUE_SP(BUF, ITER) do { \
    const int ci_ = w * 8 + (ITER) * 2 + half; \
    const float* __restrict__ spC_ = sp + (size_t)(b * 32 + ci_) * 9 * plane + h * 256; \
    _Pragma("unroll") \
    for (int k_ = 0; k_ < 9; ++k_) \
        BUF[k_] = __builtin_nontemporal_load((const f4*)(spC_ + (size_t)k_ * plane + col0)); \
} while (0)

#define COMPUTE_ITER(BUF, ITER, PREFETCH) do { \
    const int c_  = w * 8 + (ITER) * 2 + half; \
    const int bc_ = b * 32 + c_; \
    const float* __restrict__ dC_  = d  + (size_t)bc_ * plane; \
    const float* __restrict__ cdC_ = cd + (size_t)bc_ * plane; \
    float dr_[3][6], cr_[3][6]; \
    _Pragma("unroll") \
    for (int i_ = 0; i_ < 3; ++i_) { \
        const int hc_ = min(max(h + i_ - 1, 0), 255); \
        const float* __restrict__ drow_ = dC_ + hc_ * 256; \
        const float* __restrict__ crow_ = cdC_ + hc_ * 256; \
        f4 dv_ = *(const f4*)(drow_ + col0); \
        f4 cv_ = *(const f4*)(crow_ + col0); \
        dr_[i_][1] = dv_[0]; dr_[i_][2] = dv_[1]; dr_[i_][3] = dv_[2]; dr_[i_][4] = dv_[3]; \
        cr_[i_][1] = cv_[0]; cr_[i_][2] = cv_[1]; cr_[i_][3] = cv_[2]; cr_[i_][4] = cv_[3]; \
        dr_[i_][0] = drow_[max(col0 - 1, 0)]; \
        cr_[i_][0] = crow_[max(col0 - 1, 0)]; \
        dr_[i_][5] = drow_[min(col0 + 4, 255)]; \
        cr_[i_][5] = crow_[min(col0 + 4, 255)]; \
    } \
    PREFETCH; \
    float swk_[9]; \
    _Pragma("unroll") \
    for (int k_ = 0; k_ < 9; ++k_) swk_[k_] = wsbuf[c_ * 9 + k_]; \
    float nom_[4] = {0.f, 0.f, 0.f, 0.f}, den_[4] = {0.f, 0.f, 0.f, 0.f}; \
    _Pragma("unroll") \
    for (int i_ = 0; i_ < 3; ++i_) { \
        const bool rv_ = (i_ == 0) ? rowv0 : ((i_ == 2) ? rowv2 : true); \
        _Pragma("unroll") \
        for (int j_ = 0; j_ < 3; ++j_) { \
            const int k_ = i_ * 3 + j_; \
            const float s_ = swk_[k_]; \
            _Pragma("unroll") \
            for (int p_ = 0; p_ < 4; ++p_) { \
                const int ww_ = col0 + p_ + j_ - 1; \
                const bool valid_ = rv_ && ((unsigned)ww_ < 256u); \
                const float cdp_ = valid_ ? cr_[i_][p_ + j_] * BUF[k_][p_] : 0.f; \
                nom_[p_] = fmaf(cdp_ * dr_[i_][p_ + j_], s_, nom_[p_]); \
                den_[p_] = fmaf(cdp_, s_, den_[p_]); \
            } \
        } \
    } \
    /* t = cdsp*dsp = (den*inv)*(nom/(den+EPS)) ~= nom*inv (rel err EPS/(den+EPS)) */ \
    f4 tv_, cv4_; \
    _Pragma("unroll") \
    for (int p_ = 0; p_ < 4; ++p_) { \
        tv_[p_]  = nom_[p_] * inv_sum_sw; \
        cv4_[p_] = den_[p_] * inv_sum_sw; \
    } \
    *(f4*)&lt[c_ * 128 + pq * 4] = tv_; \
    *(f4*)&lc[c_ * 128 + pq * 4] = cv4_; \
} while (0)

    // ---------------- stage 1, software-pipelined ----------------
    ISSUE_SP(A, 0);
    COMPUTE_ITER(A, 0, ISSUE_SP(B, 1));
    COMPUTE_ITER(B, 1, ISSUE_SP(A, 2));
    COMPUTE_ITER(A, 2, ISSUE_SP(B, 3));
    COMPUTE_ITER(B, 3, ((void)0));

#undef ISSUE_SP
#undef COMPUTE_ITER

    __syncthreads();

    // ---------------- stage 2 (identical to fused6) ----------------
    const int og = tid >> 5;          // 0..7 -> o = og*4 .. og*4+3
    const int o0 = og * 4;

    float n2[4][4], d2[4][4];
    #pragma unroll
    for (int oi = 0; oi < 4; ++oi)
        #pragma unroll
        for (int j = 0; j < 4; ++j) { n2[oi][j] = 0.f; d2[oi][j] = 0.f; }

    for (int cc = 0; cc < 32; ++cc) {
        const f4 tq = *(const f4*)&lt[cc * 128 + pq * 4];   // ds_read_b128
        const f4 cq = *(const f4*)&lc[cc * 128 + pq * 4];   // lanes l/l+32 broadcast
        const f4 cw4 = *(const f4*)&lcw[cc * 32 + o0];
        #pragma unroll
        for (int oi = 0; oi < 4; ++oi)
            #pragma unroll
            for (int j = 0; j < 4; ++j) {
                n2[oi][j] = fmaf(tq[j], cw4[oi], n2[oi][j]);
                d2[oi][j] = fmaf(cq[j], cw4[oi], d2[oi][j]);
            }
    }

    const float inv_sum_cw = wsbuf[1313];
    const f4 b4 = *(const f4*)&bias[o0];
    const int colb = ct * 128 + pq * 4;

    #pragma unroll
    for (int oi = 0; oi < 4; ++oi) {
        f4 dv, cv;
        #pragma unroll
        for (int j = 0; j < 4; ++j) {
            dv[j] = n2[oi][j] / (d2[oi][j] + EPS) + b4[oi];
            cv[j] = d2[oi][j] * inv_sum_cw;   // STRIDE=1
        }
        const size_t po = (size_t)(b * 32 + o0 + oi) * plane + h * 256 + colb;
        *(f4*)(out + po)           = dv;
        *(f4*)(out + 8388608 + po) = cv;
    }
}

extern "C" void kernel_launch(void* const* d_in, const int* in_sizes, int n_in,
                              void* d_out, int out_size, void* d_ws, size_t ws_size,
                              hipStream_t stream) {
    const float* d    = (const float*)d_in[0];
    const float* cd   = (const float*)d_in[1];
    // d_in[2] = s, d_in[3] = cs : unused in forward
    const float* sp   = (const float*)d_in[4];
    const float* cwt  = (const float*)d_in[5];
    const float* swt  = (const float*)d_in[6];
    const float* bias = (const float*)d_in[7];
    float* out = (float*)d_out;
    float* ws  = (float*)d_ws;

    prep_weights<<<1, 256, 0, stream>>>(cwt, swt, ws);
    fused11<<<2048, 256, 0, stream>>>(d, cd, sp, ws, bias, out);
}